// Round 12
// baseline (67.588 us; speedup 1.0000x reference)
//
#include <hip/hip_runtime.h>
#include <hip/hip_bf16.h>

// T=6, B=2, Q=50 -> P=100 queries; N=8 targets; 72x72 -> 288x288 bilinear
// (align_corners=False, 4x => fixed weights); out C[B,Q,N] = 800 f32.
// R12 = R11 + (1) asm liveness-pin forcing all 48 tap loads into one batch
// (single vmcnt exposure), (2) 32-bit saddr-form tap addressing (SGPR base +
// voffset), (3) explicit v_pk_mul/fma interp. Skeleton/tail unchanged.

#define T_      6
#define P_      100
#define N_      8
#define HIN     72
#define SIN     (HIN*HIN)        // 5184
#define HOUT    288
#define S_OUT   (HOUT*HOUT)      // 82944
#define NQG     7                // query groups of 16 (100 -> 112 padded)
#define NCH     36               // pixel slabs per (t,qg): 2304 px each
#define PART_F  320              // floats per partial slot
#define WS2_OFF (T_*NQG*NCH*PART_F)          // 483840
#define NQUAD   (S_OUT/4)        // 20736 float4 per mask
#define WLDS    6144             // per-wave LDS: actL 2K, actS 2K, g 2K
#define NLOG2E  (-1.4426950408889634f)

typedef __attribute__((ext_vector_type(8))) short short8;
typedef __attribute__((ext_vector_type(4))) float f32x4;
typedef __attribute__((ext_vector_type(2))) float f32x2;

__device__ __forceinline__ unsigned cvt_pk_bf16(float lo, float hi) {
    unsigned r;
    asm("v_cvt_pk_bf16_f32 %0, %1, %2" : "=v"(r) : "v"(lo), "v"(hi));
    return r;
}
__device__ __forceinline__ f32x2 pk_mul(f32x2 a, f32x2 b) {
    f32x2 d;
    asm("v_pk_mul_f32 %0, %1, %2" : "=v"(d) : "v"(a), "v"(b));
    return d;
}
__device__ __forceinline__ f32x2 pk_fma(f32x2 a, f32x2 b, f32x2 c) {
    f32x2 d;
    asm("v_pk_fma_f32 %0, %1, %2, %3" : "=v"(d) : "v"(a), "v"(b), "v"(c));
    return d;
}

// a = sigmoid(u) where m = -log2e*u  =>  a = 1/(1+2^m)
__device__ __forceinline__ f32x2 sigm2m(f32x2 m) {
    f32x2 e;
    e.x = __builtin_amdgcn_exp2f(m.x);
    e.y = __builtin_amdgcn_exp2f(m.y);
    f32x2 d = e + 1.0f;
    f32x2 r;
    r.x = __builtin_amdgcn_rcpf(d.x);
    r.y = __builtin_amdgcn_rcpf(d.y);
    return r;
}

// ---------------------------------------------------------------------------
// Kernel 1: act pipeline + MFMA. grid = T_*NQG*NCH, 256 threads (4 waves).
// ---------------------------------------------------------------------------
__global__ __launch_bounds__(256, 4) void mfma_partial(
    const float* __restrict__ predL, const float* __restrict__ predS,
    const float* __restrict__ tgt, float* __restrict__ ws)
{
    __shared__ __align__(16) char smem[4*WLDS + 512];
    float* iredN = (float*)(smem + 4*WLDS);        // [4][16]
    float* iredD = (float*)(smem + 4*WLDS + 256);  // [4][16]
    float (*cred)[64][8] = (float (*)[64][8])smem; // aliased over act area (end only)

    const int blk = blockIdx.x;                 // (t*NQG+qg)*NCH + ch
    const int t   = blk / (NQG*NCH);
    const int rem = blk % (NQG*NCH);
    const int qg  = rem / NCH;
    const int ch  = rem % NCH;

    const int lane = threadIdx.x & 63;
    const int wv   = threadIdx.x >> 6;
    char* actL = smem + wv*WLDS;
    char* actS = actL + 2048;
    char* gpl  = actL + 4096;

    // act roles: hi = query subgroup (0..3), cell = 4-px cell (0..15)
    const int hi   = lane >> 4;
    const int cell = lane & 15;
    // uniform SGPR bases; per-block per-lane query offsets (32-bit, elements)
    const float* __restrict__ pLt = predL + (size_t)t*P_*SIN;
    const float* __restrict__ pSt = predS + (size_t)t*P_*SIN;
    int vq[4];
    bool isPad[4];
#pragma unroll
    for (int r = 0; r < 4; r++) {
        const int qglob = qg*16 + r*4 + hi;
        isPad[r] = (qglob >= P_);
        vq[r] = min(qglob, P_-1) * SIN;
    }

    // g-stage roles: n = lane>>3, f = lane&7 (two float4 each: f and f+8)
    const int gn = lane >> 3, gf = lane & 7;
    const float4* __restrict__ tgt4 = (const float4*)tgt + (size_t)t*8*NQUAD;
    const int gq0 = gn*NQUAD + gf;
    const int gwoff = (gn*128 + 8*gf) ^ ((gn&7)<<4);

    // prefill B cols 8..15 (ones column + zeros), static across iters
    if (lane < 16) {
        *(uint2*)(gpl + ((8*128 + 8*lane) ^ 0)) = make_uint2(0x3F803F80u, 0x3F803F80u);
#pragma unroll
        for (int col = 9; col < 16; col++)
            *(uint2*)(gpl + ((col*128 + 8*lane) ^ ((col&7)<<4))) = make_uint2(0u, 0u);
    }
    // qg==6: prefill pad act rows (qloc 4..15) with bf16 ones; their stores are
    // skipped below, so these rows persist -> MFMA row = sum_px(g) (tgt sums).
    if (qg == NQG-1 && lane < 12) {
        const int qloc = 4 + lane;
#pragma unroll
        for (int c8 = 0; c8 < 8; c8++) {
            const int off = (qloc*128 + 16*c8) ^ ((qloc&7)<<4);
            *(uint4*)(actL + off) = make_uint4(0x3F803F80u,0x3F803F80u,0x3F803F80u,0x3F803F80u);
            *(uint4*)(actS + off) = make_uint4(0x3F803F80u,0x3F803F80u,0x3F803F80u,0x3F803F80u);
        }
    }

    // packed weight constants (kernel-lifetime)
    const f32x2 c375 = {0.375f, 0.375f}, c625 = {0.625f, 0.625f};
    const f32x2 c125 = {0.125f, 0.125f}, c875 = {0.875f, 0.875f};

    f32x4 accL = {0.f,0.f,0.f,0.f}, accS = {0.f,0.f,0.f,0.f};
    f32x2 iN2[4], iD2[4];
#pragma unroll
    for (int r = 0; r < 4; r++) { iN2[r] = (f32x2)(0.f); iD2[r] = (f32x2)(0.f); }
    const int arow = lane & 15, kg = lane >> 4;   // MFMA fragment roles

    for (int it = 0; it < 9; it++) {
        const int px0 = ch*2304 + it*256 + wv*64;   // wave's 64-px chunk

        // --- geometry: shared by all 4 passes (depends only on cell) ---
        const unsigned p = px0 + 4*cell;
        const int row  = p / 288u;
        const int col4 = (p % 288u) >> 2;
        const int ry = row & 3, j = row >> 2;
        int y0 = (ry < 2) ? j-1 : j;
        int y1 = y0 + 1;
        y0 = max(y0, 0); y1 = min(y1, HIN-1);
        const float wt = 0.375f + 0.5f*(float)(ry>>1) - 0.25f*(float)(ry&1);
        const float wtm = wt * NLOG2E;              // fold -log2e into row weights
        const float wbm = (1.0f - wt) * NLOG2E;
        f32x2 wtm2; wtm2.x = wtm; wtm2.y = wtm;
        f32x2 wbm2; wbm2.x = wbm; wbm2.y = wbm;
        const int im1 = max(col4-1, 0), ip1 = min(col4+1, HIN-1);
        const int o0 = y0*HIN, o1 = y1*HIN;
        int vo[6];
        vo[0] = o0+im1; vo[1] = o0+col4; vo[2] = o0+ip1;
        vo[3] = o1+im1; vo[4] = o1+col4; vo[5] = o1+ip1;

        // --- LOAD BATCH: g (first, in-order) + all 48 taps (saddr+voffset) ---
        const int f4b = px0 >> 2;
        float4 ga = tgt4[gq0 + f4b];
        float4 gb = tgt4[gq0 + f4b + 8];

        f32x2 tap[4][6];   // [pass][tm,tc,tp,bm,bc,bp] ; .x = L, .y = S
#pragma unroll
        for (int r = 0; r < 4; r++) {
#pragma unroll
            for (int k = 0; k < 6; k++) {
                const int idx = vq[r] + vo[k];
                tap[r][k].x = pLt[idx];
                tap[r][k].y = pSt[idx];
            }
        }

        // --- stage g chunk (bf16, swizzled [n][k]); g loads completed first ---
        {
            uint2 pa, pb;
            pa.x = cvt_pk_bf16(ga.x, ga.y); pa.y = cvt_pk_bf16(ga.z, ga.w);
            pb.x = cvt_pk_bf16(gb.x, gb.y); pb.y = cvt_pk_bf16(gb.z, gb.w);
            *(uint2*)(gpl + gwoff) = pa;
            *(uint2*)(gpl + (gwoff ^ 64)) = pb;     // base bit6==0 pre-swz
        }

        // --- PIN: force all 24 tap f32x2 live here (one vmcnt drain) ---
        asm volatile(""
            : "+v"(tap[0][0]), "+v"(tap[0][1]), "+v"(tap[0][2]),
              "+v"(tap[0][3]), "+v"(tap[0][4]), "+v"(tap[0][5]),
              "+v"(tap[1][0]), "+v"(tap[1][1]), "+v"(tap[1][2]),
              "+v"(tap[1][3]), "+v"(tap[1][4]), "+v"(tap[1][5]),
              "+v"(tap[2][0]), "+v"(tap[2][1]), "+v"(tap[2][2]),
              "+v"(tap[2][3]), "+v"(tap[2][4]), "+v"(tap[2][5]),
              "+v"(tap[3][0]), "+v"(tap[3][1]), "+v"(tap[3][2]),
              "+v"(tap[3][3]), "+v"(tap[3][4]), "+v"(tap[3][5]));

        // --- 4 passes x 4 queries, compute from registers ---
#pragma unroll
        for (int r = 0; r < 4; r++) {
            f32x2 vm = pk_fma(tap[r][3], wbm2, pk_mul(tap[r][0], wtm2));
            f32x2 vc = pk_fma(tap[r][4], wbm2, pk_mul(tap[r][1], wtm2));
            f32x2 vp = pk_fma(tap[r][5], wbm2, pk_mul(tap[r][2], wtm2));
            f32x2 m0 = pk_fma(vc, c625, pk_mul(vm, c375));
            f32x2 m1 = pk_fma(vc, c875, pk_mul(vm, c125));
            f32x2 m2 = pk_fma(vc, c875, pk_mul(vp, c125));
            f32x2 m3 = pk_fma(vc, c625, pk_mul(vp, c375));

            f32x2 a0 = sigm2m(m0), a1 = sigm2m(m1), a2 = sigm2m(m2), a3 = sigm2m(m3);

            // conditioned IoU: u>0 <=> m<0 ; packed accumulate
            f32x2 pl01, ps01, pl23, ps23;
            pl01.x = (m0.x < 0.f) ? a0.x : 0.f;  pl01.y = (m1.x < 0.f) ? a1.x : 0.f;
            ps01.x = (m0.y < 0.f) ? a0.y : 0.f;  ps01.y = (m1.y < 0.f) ? a1.y : 0.f;
            pl23.x = (m2.x < 0.f) ? a2.x : 0.f;  pl23.y = (m3.x < 0.f) ? a3.x : 0.f;
            ps23.x = (m2.y < 0.f) ? a2.y : 0.f;  ps23.y = (m3.y < 0.f) ? a3.y : 0.f;
            iN2[r] = pk_fma(pl01, ps01, iN2[r]);
            iN2[r] = pk_fma(pl23, ps23, iN2[r]);
            iD2[r] = iD2[r] + pl01 + pl23;

            if (!isPad[r]) {
                uint2 wl, wsv;
                wl.x  = cvt_pk_bf16(a0.x, a1.x); wl.y  = cvt_pk_bf16(a2.x, a3.x);
                wsv.x = cvt_pk_bf16(a0.y, a1.y); wsv.y = cvt_pk_bf16(a2.y, a3.y);
                const int qloc = r*4 + hi;
                const int aoff = (qloc*128 + 8*cell) ^ ((qloc&7)<<4);
                *(uint2*)(actL + aoff) = wl;
                *(uint2*)(actS + aoff) = wsv;
            }
        }

        // --- MFMA: 2 k-steps x 2 tensors (wave-private LDS: no barrier) ---
#pragma unroll
        for (int ks = 0; ks < 2; ks++) {
            const int fo = (arow*128 + 64*ks + 16*kg) ^ ((arow&7)<<4);
            short8 fAL = *(const short8*)(actL + fo);
            short8 fAS = *(const short8*)(actS + fo);
            short8 fB  = *(const short8*)(gpl  + fo);
            accL = __builtin_amdgcn_mfma_f32_16x16x32_bf16(fAL, fB, accL, 0, 0, 0);
            accS = __builtin_amdgcn_mfma_f32_16x16x32_bf16(fAS, fB, accS, 0, 0, 0);
        }
    }

    // --- iou reduce within 16-lane cell groups (cell==0 holds sum) ---
    float iN[4], iD[4];
#pragma unroll
    for (int r = 0; r < 4; r++) {
        iN[r] = iN2[r].x + iN2[r].y;
        iD[r] = iD2[r].x + iD2[r].y;
        iN[r] += __shfl_down(iN[r], 1); iN[r] += __shfl_down(iN[r], 2);
        iN[r] += __shfl_down(iN[r], 4); iN[r] += __shfl_down(iN[r], 8);
        iD[r] += __shfl_down(iD[r], 1); iD[r] += __shfl_down(iD[r], 2);
        iD[r] += __shfl_down(iD[r], 4); iD[r] += __shfl_down(iD[r], 8);
    }

    __syncthreads();       // done with act LDS; cred aliases it now
#pragma unroll
    for (int e = 0; e < 4; e++) { cred[wv][lane][e] = accL[e]; cred[wv][lane][4+e] = accS[e]; }
    if (cell == 0) {
#pragma unroll
        for (int r = 0; r < 4; r++) {
            iredN[wv*16 + r*4 + hi] = iN[r];
            iredD[wv*16 + r*4 + hi] = iD[r];
        }
    }
    __syncthreads();

    float* wsb = ws + (size_t)blk * PART_F;
    if (threadIdx.x < 64) {
        const int l = threadIdx.x;
        const int colx = l & 15, rb = (l >> 4) * 4;
        if (colx < 9) {
#pragma unroll
            for (int e = 0; e < 4; e++) {
                const float sLv = cred[0][l][e]+cred[1][l][e]+cred[2][l][e]+cred[3][l][e];
                const float sSv = cred[0][l][4+e]+cred[1][l][4+e]+cred[2][l][4+e]+cred[3][l][4+e];
                wsb[colx*16 + rb + e] = sLv;
                wsb[144 + colx*16 + rb + e] = sSv;
            }
        }
    }
    if (threadIdx.x < 16) {
        wsb[288 + threadIdx.x] = iredN[threadIdx.x] + iredN[16+threadIdx.x]
                               + iredN[32+threadIdx.x] + iredN[48+threadIdx.x];
        wsb[304 + threadIdx.x] = iredD[threadIdx.x] + iredD[16+threadIdx.x]
                               + iredD[32+threadIdx.x] + iredD[48+threadIdx.x];
    }
}

// ---------------------------------------------------------------------------
// Kernel 2: reduce NCH chunk partials -> per-(t,qg) sums
// ---------------------------------------------------------------------------
__global__ __launch_bounds__(320) void reduce_kernel(float* __restrict__ ws)
{
    const int tq = blockIdx.x;               // t*NQG + qg
    for (int s = threadIdx.x; s < PART_F; s += 320) {
        float acc = 0.f;
        const float* base = ws + (size_t)tq*NCH*PART_F + s;
#pragma unroll 4
        for (int c = 0; c < NCH; c++) acc += base[(size_t)c*PART_F];
        ws[WS2_OFF + (size_t)tq*PART_F + s] = acc;
    }
}

// ---------------------------------------------------------------------------
// Kernel 3: finalize 800 outputs (gS from qg=6 pad ones-rows, row 4)
// ---------------------------------------------------------------------------
__global__ __launch_bounds__(64) void final_kernel(
    const float* __restrict__ pirL, const float* __restrict__ pirS,
    const int* __restrict__ refidx, const float* __restrict__ ws,
    float* __restrict__ out)
{
    const int gid = blockIdx.x*64 + threadIdx.x;
    if (gid >= P_*N_) return;
    const int p = gid >> 3, n = gid & 7;
    const int b = p / 50, qloc = p % 50;
    const int qg = p >> 4, row = p & 15;
    const int rg0 = refidx[0], rg1 = refidx[1] + 4;   // ref_indices[b] + b*(N/B)
    const bool isref = (n == rg0) || (n == rg1);

    float acc = 0.f;
    for (int t = 0; t < T_; t++) {
        const float* b2 = ws + WS2_OFF + (size_t)(t*NQG + qg)*PART_F;
        const float dL = b2[n*16 + row];
        const float sL = b2[128 + row];          // ones column (col 8)
        const float dS = b2[144 + n*16 + row];
        const float sS = b2[144 + 128 + row];
        const float iN = b2[288 + row];
        const float iD = b2[304 + row];
        // tgt sum from qg=6 pad ones-row (row 4 = first pad query)
        const float gS = ws[WS2_OFF + (size_t)(t*NQG + (NQG-1))*PART_F + n*16 + 4];

        const float diceL = (2.f*dL + 1.f) / (sL + gS + 1.f);
        const float diceS = (2.f*dS + 1.f) / (sS + gS + 1.f);
        const float iou   = (iN + 1.f) / (iD + 1.f);
        const int ib = ((t*2 + b)*50 + qloc)*2;
        const float l0 = pirL[ib], l1 = pirL[ib+1];
        const float m0 = pirS[ib], m1 = pirS[ib+1];
        const float pl = isref ? 1.f/(1.f + __expf(l1 - l0)) : 1.f/(1.f + __expf(l0 - l1));
        const float ps = isref ? 1.f/(1.f + __expf(m1 - m0)) : 1.f/(1.f + __expf(m0 - m1));
        acc += diceL + diceS + iou + pl + ps;
    }
    out[gid] = -acc * (1.0f / (float)T_);
}

extern "C" void kernel_launch(void* const* d_in, const int* in_sizes, int n_in,
                              void* d_out, int out_size, void* d_ws, size_t ws_size,
                              hipStream_t stream) {
    const float* predL = (const float*)d_in[0];   // [6,2,50,72,72]
    const float* predS = (const float*)d_in[1];   // [6,2,50,72,72]
    const float* pirL  = (const float*)d_in[2];   // [6,2,50,2]
    const float* pirS  = (const float*)d_in[3];   // [6,2,50,2]
    const float* tgt   = (const float*)d_in[4];   // [6,8,288,288]
    const int*   refix = (const int*)d_in[5];     // [2]
    float* ws  = (float*)d_ws;                    // ~497,280 floats (~1.99 MB)
    float* out = (float*)d_out;                   // 800 floats

    mfma_partial<<<T_*NQG*NCH, 256, 0, stream>>>(predL, predS, tgt, ws);
    reduce_kernel<<<T_*NQG, 320, 0, stream>>>(ws);
    final_kernel<<<(P_*N_ + 63)/64, 64, 0, stream>>>(pirL, pirS, refix, ws, out);
}